// Round 4
// baseline (4650.480 us; speedup 1.0000x reference)
//
#include <hip/hip_runtime.h>

// SGAT layer — fp32 inputs/outputs (reference is jnp.float32 throughout; the
// "bf16" in the harness label is the TOLERANCE mode, not storage: R1-R3 NaN'd
// because fp32 data was read as packed bf16 -> garbage -> exp overflow -> NaN).
// Structure: fold W_e*a_edge -> B[128][4]; Wh = h@W via bf16 MFMA (fp32->bf16
// on load, error ~3e-4 << 1.17e-3 threshold); per-node s_src/s_dst; global
// softmax w/o max-subtraction (scores ~N(0,2.4^2), exp safe in fp32); sums via
// per-block partials + tree reduce (no atomics); scatter via fp32 atomicAdd;
// normalization folded into epilogue (relu(x)/s == relu(x/s), s>0).

typedef __attribute__((ext_vector_type(8))) short short8;
typedef __attribute__((ext_vector_type(4))) float f32x4;

#define ALPHA 0.2f

__device__ __forceinline__ unsigned short f2bf(float f) {
    unsigned u = __float_as_uint(f);
    u += 0x7fffu + ((u >> 16) & 1u);
    return (unsigned short)(u >> 16);
}
__device__ __forceinline__ float bf2f(unsigned short u) {
    return __uint_as_float(((unsigned)u) << 16);
}

// B[k][h] = sum_d We[k][h*32+d] * a_edge[h*32+d]   (128x4, k-major)
__global__ void fold_kernel(const float* __restrict__ We,
                            const float* __restrict__ a_edge,
                            float* __restrict__ Bfold) {
    int k = threadIdx.x;  // 128 threads
    for (int h = 0; h < 4; h++) {
        float acc = 0.f;
        for (int d = 0; d < 32; d++)
            acc += We[k * 128 + h * 32 + d] * a_edge[h * 32 + d];
        Bfold[k * 4 + h] = acc;
    }
}

// Wh = h @ W : [N,128]x[128,128], fp32 in -> bf16 MFMA 16x16x32 -> bf16 out.
__global__ __launch_bounds__(256) void gemm_wh(const float* __restrict__ hmat,
                                               const float* __restrict__ W,
                                               unsigned short* __restrict__ Whb, int N) {
    __shared__ short Wb[16384];  // 32KB, [nt][ks][lane][j] fragment-contiguous
    int tid = threadIdx.x;
    for (int i = tid; i < 16384; i += 256) {
        int j = i & 7, lane = (i >> 3) & 63, ks = (i >> 9) & 3, nt = (i >> 11) & 7;
        int m = lane & 15, quad = lane >> 4;
        int k = ks * 32 + quad * 8 + j;
        int c = nt * 16 + m;
        Wb[i] = (short)f2bf(W[k * 128 + c]);
    }
    __syncthreads();
    int wave = tid >> 6, lane = tid & 63;
    int m = lane & 15, quad = lane >> 4;
    int row0 = blockIdx.x * 64 + wave * 16;
    int row = row0 + m;
    if (row >= N) row = N - 1;  // clamp loads; stores guarded below
    const float* hrow = hmat + (size_t)row * 128;
    short8 af[4];
    for (int ks = 0; ks < 4; ks++) {
        f32x4 lo = *(const f32x4*)(hrow + ks * 32 + quad * 8);
        f32x4 hi = *(const f32x4*)(hrow + ks * 32 + quad * 8 + 4);
        short8 a;
        a[0] = (short)f2bf(lo.x); a[1] = (short)f2bf(lo.y);
        a[2] = (short)f2bf(lo.z); a[3] = (short)f2bf(lo.w);
        a[4] = (short)f2bf(hi.x); a[5] = (short)f2bf(hi.y);
        a[6] = (short)f2bf(hi.z); a[7] = (short)f2bf(hi.w);
        af[ks] = a;
    }
    for (int nt = 0; nt < 8; nt++) {
        f32x4 acc = {0.f, 0.f, 0.f, 0.f};
        for (int ks = 0; ks < 4; ks++) {
            short8 bf = *(const short8*)(Wb + ((nt * 4 + ks) * 64 + lane) * 8);
            acc = __builtin_amdgcn_mfma_f32_16x16x32_bf16(af[ks], bf, acc, 0, 0, 0);
        }
        // C/D: col = lane&15, row = quad*4 + r   [verified m89/m91]
        for (int r = 0; r < 4; r++) {
            int orow = row0 + quad * 4 + r;
            if (orow < N) Whb[(size_t)orow * 128 + nt * 16 + m] = f2bf(acc[r]);
        }
    }
}

// s_src[n,h] = Wh[n,h*32:].a_src[h]; same for dst. One thread per (n,h).
__global__ void sdot_kernel(const unsigned short* __restrict__ Whb,
                            const float* __restrict__ a_src,
                            const float* __restrict__ a_dst,
                            float* __restrict__ s_src, float* __restrict__ s_dst, int N) {
    int t = blockIdx.x * blockDim.x + threadIdx.x;
    if (t >= N * 4) return;
    int n = t >> 2, hh = t & 3;
    const short* w = (const short*)Whb + (size_t)n * 128 + hh * 32;
    float ss = 0.f, sd = 0.f;
    for (int c = 0; c < 4; c++) {
        short8 wv = *(const short8*)(w + c * 8);
#pragma unroll
        for (int j = 0; j < 8; j++) {
            float v = bf2f((unsigned short)wv[j]);
            ss += v * a_src[hh * 32 + c * 8 + j];
            sd += v * a_dst[hh * 32 + c * 8 + j];
        }
    }
    s_src[t] = ss;
    s_dst[t] = sd;
}

// Per edge: score = ef.B + s_src[src] + s_dst[dst]; lrelu; p=exp;
// per-block partial sums -> P[block][4]; scatter p*Wh[src] into hprime[dst].
__global__ __launch_bounds__(256) void edge_kernel(
        const int* __restrict__ ei, const float* __restrict__ ef,
        const float* __restrict__ Bfold, const float* __restrict__ s_src,
        const float* __restrict__ s_dst, const unsigned short* __restrict__ Whb,
        float* __restrict__ hprime, float* __restrict__ P, int E) {
    __shared__ float ps[16];
    int tid = threadIdx.x;
    long e = (long)blockIdx.x * 256 + tid;
    bool valid = e < E;
    int srcn = 0, dstn = 0;
    float p0 = 0.f, p1 = 0.f, p2 = 0.f, p3 = 0.f;
    if (valid) {
        float a0 = 0.f, a1 = 0.f, a2 = 0.f, a3 = 0.f;
        const f32x4* xr = (const f32x4*)(ef + (size_t)e * 128);
        const f32x4* B4 = (const f32x4*)Bfold;  // wave-uniform -> scalar loads
#pragma unroll 8
        for (int ch = 0; ch < 32; ch++) {
            f32x4 xv = xr[ch];
#pragma unroll
            for (int j = 0; j < 4; j++) {
                float xf = xv[j];
                f32x4 b = B4[ch * 4 + j];
                a0 += xf * b.x; a1 += xf * b.y; a2 += xf * b.z; a3 += xf * b.w;
            }
        }
        srcn = ei[e];
        dstn = ei[(size_t)E + e];
        f32x4 svs = ((const f32x4*)s_src)[srcn];
        f32x4 svd = ((const f32x4*)s_dst)[dstn];
        float t0 = a0 + svs.x + svd.x;
        float t1 = a1 + svs.y + svd.y;
        float t2 = a2 + svs.z + svd.z;
        float t3 = a3 + svs.w + svd.w;
        t0 = t0 >= 0.f ? t0 : ALPHA * t0;
        t1 = t1 >= 0.f ? t1 : ALPHA * t1;
        t2 = t2 >= 0.f ? t2 : ALPHA * t2;
        t3 = t3 >= 0.f ? t3 : ALPHA * t3;
        p0 = expf(t0); p1 = expf(t1); p2 = expf(t2); p3 = expf(t3);
    }
    // per-wave butterfly reduce -> per-block partial (no atomics)
    float r0 = p0, r1 = p1, r2 = p2, r3 = p3;
    for (int off = 32; off > 0; off >>= 1) {
        r0 += __shfl_xor(r0, off);
        r1 += __shfl_xor(r1, off);
        r2 += __shfl_xor(r2, off);
        r3 += __shfl_xor(r3, off);
    }
    if ((tid & 63) == 0) {
        int w = tid >> 6;
        ps[w * 4 + 0] = r0; ps[w * 4 + 1] = r1; ps[w * 4 + 2] = r2; ps[w * 4 + 3] = r3;
    }
    __syncthreads();
    if (tid < 4)
        P[(size_t)blockIdx.x * 4 + tid] = ps[tid] + ps[4 + tid] + ps[8 + tid] + ps[12 + tid];

    if (valid) {
        const short8* wr = (const short8*)(Whb + (size_t)srcn * 128);
        float* hp = hprime + (size_t)dstn * 128;
        float pv[4] = {p0, p1, p2, p3};
#pragma unroll
        for (int h = 0; h < 4; h++) {
            float ph = pv[h];
#pragma unroll
            for (int q = 0; q < 4; q++) {
                short8 w = wr[h * 4 + q];
#pragma unroll
                for (int j = 0; j < 8; j++)
                    atomicAdd(hp + h * 32 + q * 8 + j, ph * bf2f((unsigned short)w[j]));
            }
        }
    }
}

// sums[h] = sum over blocks of P[b][h]; tree reduce, no atomics
__global__ void reduce_sums(const float* __restrict__ P, float* __restrict__ sums, int nb) {
    __shared__ float red[256];
    int t = threadIdx.x;
    float acc = 0.f;
    for (int b = t >> 2; b < nb; b += 64) acc += P[(size_t)b * 4 + (t & 3)];
    red[t] = acc;
    __syncthreads();
    for (int s = 128; s >= 4; s >>= 1) {
        if (t < s) red[t] += red[t + s];
        __syncthreads();
    }
    if (t < 4) sums[t] = red[t];
}

// out = relu(hprime) / sums[head]; fp32 out, one thread per float4
__global__ void epi_kernel(const float* __restrict__ hprime, const float* __restrict__ sums,
                           float* __restrict__ out, int total4) {
    int t = blockIdx.x * blockDim.x + threadIdx.x;
    if (t >= total4) return;
    f32x4 v = ((const f32x4*)hprime)[t];
    int hh = (t >> 3) & 3;  // col4-group within row = t&31; head = group>>3
    float inv = 1.0f / sums[hh];
    f32x4 o;
    o.x = fmaxf(v.x, 0.f) * inv;
    o.y = fmaxf(v.y, 0.f) * inv;
    o.z = fmaxf(v.z, 0.f) * inv;
    o.w = fmaxf(v.w, 0.f) * inv;
    ((f32x4*)out)[t] = o;
}

extern "C" void kernel_launch(void* const* d_in, const int* in_sizes, int n_in,
                              void* d_out, int out_size, void* d_ws, size_t ws_size,
                              hipStream_t stream) {
    const int* ei = (const int*)d_in[0];
    const float* hmat = (const float*)d_in[1];
    const float* ef = (const float*)d_in[2];
    const float* W = (const float*)d_in[3];
    const float* We = (const float*)d_in[4];
    const float* a_src = (const float*)d_in[5];
    const float* a_dst = (const float*)d_in[6];
    const float* a_edge = (const float*)d_in[7];
    int E = in_sizes[0] / 2;
    int N = in_sizes[1] / 128;
    int nEdgeBlocks = (E + 255) / 256;

    char* ws = (char*)d_ws;
    size_t off = 0;
    auto alloc = [&](size_t bytes) -> void* {
        void* p = ws + off;
        off = (off + bytes + 255) & ~(size_t)255;
        return p;
    };
    unsigned short* Whb = (unsigned short*)alloc((size_t)N * 128 * 2);
    float* s_src = (float*)alloc((size_t)N * 4 * 4);
    float* s_dst = (float*)alloc((size_t)N * 4 * 4);
    float* Bfold = (float*)alloc(128 * 4 * 4);
    float* hprime = (float*)alloc((size_t)N * 128 * 4);
    float* P = (float*)alloc((size_t)nEdgeBlocks * 4 * 4);
    float* sums = (float*)alloc(256);

    hipMemsetAsync(hprime, 0, (size_t)N * 128 * 4, stream);
    fold_kernel<<<1, 128, 0, stream>>>(We, a_edge, Bfold);
    gemm_wh<<<(N + 63) / 64, 256, 0, stream>>>(hmat, W, Whb, N);
    sdot_kernel<<<(N * 4 + 255) / 256, 256, 0, stream>>>(Whb, a_src, a_dst, s_src, s_dst, N);
    edge_kernel<<<nEdgeBlocks, 256, 0, stream>>>(ei, ef, Bfold, s_src, s_dst, Whb,
                                                 hprime, P, E);
    reduce_sums<<<1, 256, 0, stream>>>(P, sums, nEdgeBlocks);
    int total4 = N * 128 / 4;
    epi_kernel<<<(total4 + 255) / 256, 256, 0, stream>>>(hprime, sums,
                                                         (float*)d_out, total4);
}

// Round 5
// 711.611 us; speedup vs baseline: 6.5351x; 6.5351x over previous
//
#include <hip/hip_runtime.h>

// SGAT layer — fp32 in/out. R5: kill the 82M-fp-atomic scatter (R4: 4268us,
// VALUBusy 0.26%, WRITE_SIZE 2.56GB = atomics RMW at memory, 19 G atomics/s).
// Replace with counting-sort by dst (hist + scan + bucket write, 1.3M int
// atomics total) + per-node gather aggregation (register accumulate, direct
// final output; hprime/memset/epilogue eliminated).
// Kept from R4 (passed, absmax 3.7e-4): fold W_e*a_edge -> B[128][4]; bf16 MFMA
// for Wh (stored bf16, halves gather bytes); global softmax w/o max-subtract;
// per-block exp-sum partials + tree reduce (atomic-free).

typedef __attribute__((ext_vector_type(8))) short short8;
typedef __attribute__((ext_vector_type(4))) float f32x4;

#define ALPHA 0.2f

__device__ __forceinline__ unsigned short f2bf(float f) {
    unsigned u = __float_as_uint(f);
    u += 0x7fffu + ((u >> 16) & 1u);
    return (unsigned short)(u >> 16);
}
__device__ __forceinline__ float bf2f(unsigned short u) {
    return __uint_as_float(((unsigned)u) << 16);
}

// B[k][h] = sum_d We[k][h*32+d] * a_edge[h*32+d]   (128x4, k-major)
__global__ void fold_kernel(const float* __restrict__ We,
                            const float* __restrict__ a_edge,
                            float* __restrict__ Bfold) {
    int k = threadIdx.x;  // 128 threads
    for (int h = 0; h < 4; h++) {
        float acc = 0.f;
        for (int d = 0; d < 32; d++)
            acc += We[k * 128 + h * 32 + d] * a_edge[h * 32 + d];
        Bfold[k * 4 + h] = acc;
    }
}

// deg[dst]++ over all edges
__global__ void hist_kernel(const int* __restrict__ ei, int* __restrict__ deg, int E) {
    int e = blockIdx.x * blockDim.x + threadIdx.x;
    if (e < E) atomicAdd(&deg[ei[(size_t)E + e]], 1);
}

// single-block exclusive prefix sum: off[i] = sum deg[0..i), off[N] = E; cursor = off
__global__ __launch_bounds__(1024) void scan_kernel(const int* __restrict__ deg,
                                                    int* __restrict__ off,
                                                    int* __restrict__ cursor, int N) {
    __shared__ int buf[1024];
    int t = threadIdx.x;
    int base = 0;
    for (int start = 0; start < N; start += 8192) {
        int v[8];
        int tsum = 0;
#pragma unroll
        for (int j = 0; j < 8; j++) {
            int i = start + t * 8 + j;
            v[j] = (i < N) ? deg[i] : 0;
            tsum += v[j];
        }
        buf[t] = tsum;
        __syncthreads();
        for (int st = 1; st < 1024; st <<= 1) {
            int x = buf[t];
            int y = (t >= st) ? buf[t - st] : 0;
            __syncthreads();
            buf[t] = x + y;
            __syncthreads();
        }
        int excl = base + buf[t] - tsum;
        int chunk_total = buf[1023];
#pragma unroll
        for (int j = 0; j < 8; j++) {
            int i = start + t * 8 + j;
            if (i < N) { off[i] = excl; cursor[i] = excl; }
            excl += v[j];
        }
        base += chunk_total;
        __syncthreads();
    }
    if (t == 0) off[N] = base;
}

// Wh = h @ W : [N,128]x[128,128], fp32 in -> bf16 MFMA 16x16x32 -> bf16 out.
__global__ __launch_bounds__(256) void gemm_wh(const float* __restrict__ hmat,
                                               const float* __restrict__ W,
                                               unsigned short* __restrict__ Whb, int N) {
    __shared__ short Wb[16384];  // 32KB, [nt][ks][lane][j] fragment-contiguous
    int tid = threadIdx.x;
    for (int i = tid; i < 16384; i += 256) {
        int j = i & 7, lane = (i >> 3) & 63, ks = (i >> 9) & 3, nt = (i >> 11) & 7;
        int m = lane & 15, quad = lane >> 4;
        int k = ks * 32 + quad * 8 + j;
        int c = nt * 16 + m;
        Wb[i] = (short)f2bf(W[k * 128 + c]);
    }
    __syncthreads();
    int wave = tid >> 6, lane = tid & 63;
    int m = lane & 15, quad = lane >> 4;
    int row0 = blockIdx.x * 64 + wave * 16;
    int row = row0 + m;
    if (row >= N) row = N - 1;  // clamp loads; stores guarded below
    const float* hrow = hmat + (size_t)row * 128;
    short8 af[4];
    for (int ks = 0; ks < 4; ks++) {
        f32x4 lo = *(const f32x4*)(hrow + ks * 32 + quad * 8);
        f32x4 hi = *(const f32x4*)(hrow + ks * 32 + quad * 8 + 4);
        short8 a;
        a[0] = (short)f2bf(lo.x); a[1] = (short)f2bf(lo.y);
        a[2] = (short)f2bf(lo.z); a[3] = (short)f2bf(lo.w);
        a[4] = (short)f2bf(hi.x); a[5] = (short)f2bf(hi.y);
        a[6] = (short)f2bf(hi.z); a[7] = (short)f2bf(hi.w);
        af[ks] = a;
    }
    for (int nt = 0; nt < 8; nt++) {
        f32x4 acc = {0.f, 0.f, 0.f, 0.f};
        for (int ks = 0; ks < 4; ks++) {
            short8 bf = *(const short8*)(Wb + ((nt * 4 + ks) * 64 + lane) * 8);
            acc = __builtin_amdgcn_mfma_f32_16x16x32_bf16(af[ks], bf, acc, 0, 0, 0);
        }
        // C/D: col = lane&15, row = quad*4 + r   [verified m89/m91]
        for (int r = 0; r < 4; r++) {
            int orow = row0 + quad * 4 + r;
            if (orow < N) Whb[(size_t)orow * 128 + nt * 16 + m] = f2bf(acc[r]);
        }
    }
}

// s_src[n,h] = Wh[n,h*32:].a_src[h]; same for dst. One thread per (n,h).
__global__ void sdot_kernel(const unsigned short* __restrict__ Whb,
                            const float* __restrict__ a_src,
                            const float* __restrict__ a_dst,
                            float* __restrict__ s_src, float* __restrict__ s_dst, int N) {
    int t = blockIdx.x * blockDim.x + threadIdx.x;
    if (t >= N * 4) return;
    int n = t >> 2, hh = t & 3;
    const short* w = (const short*)Whb + (size_t)n * 128 + hh * 32;
    float ss = 0.f, sd = 0.f;
    for (int c = 0; c < 4; c++) {
        short8 wv = *(const short8*)(w + c * 8);
#pragma unroll
        for (int j = 0; j < 8; j++) {
            float v = bf2f((unsigned short)wv[j]);
            ss += v * a_src[hh * 32 + c * 8 + j];
            sd += v * a_dst[hh * 32 + c * 8 + j];
        }
    }
    s_src[t] = ss;
    s_dst[t] = sd;
}

// Per edge: score = ef.B + s_src[src] + s_dst[dst]; lrelu; p=exp;
// per-block partial exp-sums -> P; bucket write {src, p} at cursor[dst]++.
__global__ __launch_bounds__(256) void edge_kernel(
        const int* __restrict__ ei, const float* __restrict__ ef,
        const float* __restrict__ Bfold, const float* __restrict__ s_src,
        const float* __restrict__ s_dst, int* __restrict__ cursor,
        int* __restrict__ bsrc, f32x4* __restrict__ bp,
        float* __restrict__ P, int E) {
    __shared__ float ps[16];
    int tid = threadIdx.x;
    long e = (long)blockIdx.x * 256 + tid;
    bool valid = e < E;
    float p0 = 0.f, p1 = 0.f, p2 = 0.f, p3 = 0.f;
    if (valid) {
        float a0 = 0.f, a1 = 0.f, a2 = 0.f, a3 = 0.f;
        const f32x4* xr = (const f32x4*)(ef + (size_t)e * 128);
        const f32x4* B4 = (const f32x4*)Bfold;  // wave-uniform -> scalar loads
#pragma unroll 8
        for (int ch = 0; ch < 32; ch++) {
            f32x4 xv = xr[ch];
#pragma unroll
            for (int j = 0; j < 4; j++) {
                float xf = xv[j];
                f32x4 b = B4[ch * 4 + j];
                a0 += xf * b.x; a1 += xf * b.y; a2 += xf * b.z; a3 += xf * b.w;
            }
        }
        int srcn = ei[e];
        int dstn = ei[(size_t)E + e];
        f32x4 svs = ((const f32x4*)s_src)[srcn];
        f32x4 svd = ((const f32x4*)s_dst)[dstn];
        float t0 = a0 + svs.x + svd.x;
        float t1 = a1 + svs.y + svd.y;
        float t2 = a2 + svs.z + svd.z;
        float t3 = a3 + svs.w + svd.w;
        t0 = t0 >= 0.f ? t0 : ALPHA * t0;
        t1 = t1 >= 0.f ? t1 : ALPHA * t1;
        t2 = t2 >= 0.f ? t2 : ALPHA * t2;
        t3 = t3 >= 0.f ? t3 : ALPHA * t3;
        p0 = expf(t0); p1 = expf(t1); p2 = expf(t2); p3 = expf(t3);
        int pos = atomicAdd(&cursor[dstn], 1);
        bsrc[pos] = srcn;
        f32x4 pv = {p0, p1, p2, p3};
        bp[pos] = pv;
    }
    // per-wave butterfly reduce -> per-block partial (no atomics)
    float r0 = p0, r1 = p1, r2 = p2, r3 = p3;
    for (int off = 32; off > 0; off >>= 1) {
        r0 += __shfl_xor(r0, off);
        r1 += __shfl_xor(r1, off);
        r2 += __shfl_xor(r2, off);
        r3 += __shfl_xor(r3, off);
    }
    if ((tid & 63) == 0) {
        int w = tid >> 6;
        ps[w * 4 + 0] = r0; ps[w * 4 + 1] = r1; ps[w * 4 + 2] = r2; ps[w * 4 + 3] = r3;
    }
    __syncthreads();
    if (tid < 4)
        P[(size_t)blockIdx.x * 4 + tid] = ps[tid] + ps[4 + tid] + ps[8 + tid] + ps[12 + tid];
}

// sums[h] = sum over blocks of P[b][h]; tree reduce, no atomics
__global__ void reduce_sums(const float* __restrict__ P, float* __restrict__ sums, int nb) {
    __shared__ float red[256];
    int t = threadIdx.x;
    float acc = 0.f;
    for (int b = t >> 2; b < nb; b += 64) acc += P[(size_t)b * 4 + (t & 3)];
    red[t] = acc;
    __syncthreads();
    for (int s = 128; s >= 4; s >>= 1) {
        if (t < s) red[t] += red[t + s];
        __syncthreads();
    }
    if (t < 4) sums[t] = red[t];
}

// One wave per dst node: walk bucket, acc += p[head] * Whb[src], then
// out = relu(acc) / sums[head]. Lane l owns cols 2l, 2l+1 (same head).
__global__ __launch_bounds__(256) void agg_kernel(
        const int* __restrict__ off, const int* __restrict__ bsrc,
        const float* __restrict__ bp, const unsigned short* __restrict__ Whb,
        const float* __restrict__ sums, float* __restrict__ out, int N) {
    int wave = threadIdx.x >> 6, lane = threadIdx.x & 63;
    int n = blockIdx.x * 4 + wave;
    if (n >= N) return;
    int i0 = off[n], i1 = off[n + 1];
    int head = lane >> 4;  // col = 2*lane -> head = 2*lane/32 = lane/16
    float acc0 = 0.f, acc1 = 0.f;
    for (int i = i0; i < i1; i++) {
        int src = bsrc[i];
        float ph = bp[(size_t)i * 4 + head];
        unsigned w = *(const unsigned*)(Whb + (size_t)src * 128 + lane * 2);
        acc0 += ph * bf2f((unsigned short)(w & 0xffffu));
        acc1 += ph * bf2f((unsigned short)(w >> 16));
    }
    float inv = 1.0f / sums[head];
    float2 o;
    o.x = fmaxf(acc0, 0.f) * inv;
    o.y = fmaxf(acc1, 0.f) * inv;
    *(float2*)(out + (size_t)n * 128 + lane * 2) = o;
}

extern "C" void kernel_launch(void* const* d_in, const int* in_sizes, int n_in,
                              void* d_out, int out_size, void* d_ws, size_t ws_size,
                              hipStream_t stream) {
    const int* ei = (const int*)d_in[0];
    const float* hmat = (const float*)d_in[1];
    const float* ef = (const float*)d_in[2];
    const float* W = (const float*)d_in[3];
    const float* We = (const float*)d_in[4];
    const float* a_src = (const float*)d_in[5];
    const float* a_dst = (const float*)d_in[6];
    const float* a_edge = (const float*)d_in[7];
    int E = in_sizes[0] / 2;
    int N = in_sizes[1] / 128;
    int nEdgeBlocks = (E + 255) / 256;

    char* ws = (char*)d_ws;
    size_t off_b = 0;
    auto alloc = [&](size_t bytes) -> void* {
        void* p = ws + off_b;
        off_b = (off_b + bytes + 255) & ~(size_t)255;
        return p;
    };
    unsigned short* Whb = (unsigned short*)alloc((size_t)N * 128 * 2);
    float* s_src = (float*)alloc((size_t)N * 4 * 4);
    float* s_dst = (float*)alloc((size_t)N * 4 * 4);
    float* Bfold = (float*)alloc(128 * 4 * 4);
    int* deg = (int*)alloc((size_t)N * 4);
    int* off = (int*)alloc((size_t)(N + 1) * 4);
    int* cursor = (int*)alloc((size_t)N * 4);
    int* bsrc = (int*)alloc((size_t)E * 4);
    float* bp = (float*)alloc((size_t)E * 16);
    float* P = (float*)alloc((size_t)nEdgeBlocks * 4 * 4);
    float* sums = (float*)alloc(256);

    hipMemsetAsync(deg, 0, (size_t)N * 4, stream);
    fold_kernel<<<1, 128, 0, stream>>>(We, a_edge, Bfold);
    hist_kernel<<<(E + 255) / 256, 256, 0, stream>>>(ei, deg, E);
    scan_kernel<<<1, 1024, 0, stream>>>(deg, off, cursor, N);
    gemm_wh<<<(N + 63) / 64, 256, 0, stream>>>(hmat, W, Whb, N);
    sdot_kernel<<<(N * 4 + 255) / 256, 256, 0, stream>>>(Whb, a_src, a_dst, s_src, s_dst, N);
    edge_kernel<<<nEdgeBlocks, 256, 0, stream>>>(ei, ef, Bfold, s_src, s_dst,
                                                 cursor, bsrc, (f32x4*)bp, P, E);
    reduce_sums<<<1, 256, 0, stream>>>(P, sums, nEdgeBlocks);
    agg_kernel<<<(N + 3) / 4, 256, 0, stream>>>(off, bsrc, bp, Whb, sums,
                                                (float*)d_out, N);
}